// Round 10
// baseline (823.561 us; speedup 1.0000x reference)
//
#include <hip/hip_runtime.h>
#include <hip/hip_fp16.h>

constexpr int NN = 100000;   // nodes
constexpr int EE = 3200000;  // edges
constexpr int GG = 5000;     // graphs
constexpr float BNEPS = 1e-5f;

constexpr int XCDS = 8;
constexpr int NODES_PER_XCD = (NN + XCDS - 1) / XCDS;  // 12500

constexpr int SCAN_BLK = 256;
constexpr int SCAN_ITEMS = 1024;                       // 256 thr x 4
constexpr int NSCANBLK = (NN + SCAN_ITEMS - 1) / SCAN_ITEMS;  // 98

// edge binning
constexpr int OCTCAP_REGION = 408576;  // per-octant pair region
constexpr int BINCAP = 320;            // LDS staging per octant per chunk
constexpr int CHUNK = 1024;            // edges per block-batch (bin pass)
constexpr int NCHUNK = EE / CHUNK;     // 3125
constexpr int WCHUNK = 1024;           // edges per stolen chunk (count/scatter)
constexpr int CTR_STRIDE = 32;         // pad counters to separate 128B lines

typedef int int4v __attribute__((ext_vector_type(4)));

__device__ __forceinline__ int get_xcc() {
    unsigned v;
    asm volatile("s_getreg_b32 %0, hwreg(20, 0, 32)" : "=s"(v));  // HW_REG_XCC_ID
    return (int)(v & 7);
}

// ---------------- pass 1: bin edges by dst octant, sequential pair writes ----------------

__global__ void bin_edges(const int* __restrict__ ei, uint2* __restrict__ pairs,
                          int* __restrict__ octCur) {
    __shared__ int bcnt[8];
    __shared__ int bbase[8];
    __shared__ uint2 buf[8][BINCAP];
    const int t = threadIdx.x;
    for (int ch = blockIdx.x; ch < NCHUNK; ch += gridDim.x) {
        if (t < 8) bcnt[t] = 0;
        __syncthreads();
        const int q = ch * (CHUNK / 4) + t;  // int4 index
        int4v d = __builtin_nontemporal_load((const int4v*)(ei + EE) + q);
        int4v s = __builtin_nontemporal_load((const int4v*)ei + q);
        int dd[4] = {d.x, d.y, d.z, d.w};
        int ss[4] = {s.x, s.y, s.z, s.w};
#pragma unroll
        for (int k = 0; k < 4; ++k) {
            int o = dd[k] / NODES_PER_XCD;
            int p = atomicAdd(&bcnt[o], 1);
            if (p < BINCAP) {
                buf[o][p] = make_uint2((unsigned)dd[k], (unsigned)ss[k]);
            } else {  // overflow: rare direct write
                int gp = atomicAdd(&octCur[o * CTR_STRIDE], 1);
                pairs[(size_t)o * OCTCAP_REGION + gp] = make_uint2((unsigned)dd[k], (unsigned)ss[k]);
            }
        }
        __syncthreads();
        if (t < 8) {
            int c = bcnt[t] < BINCAP ? bcnt[t] : BINCAP;
            bbase[t] = atomicAdd(&octCur[t * CTR_STRIDE], c);
            bcnt[t] = c;
        }
        __syncthreads();
#pragma unroll
        for (int o = 0; o < 8; ++o) {
            const int c = bcnt[o];
            const size_t base = (size_t)o * OCTCAP_REGION + bbase[o];
            for (int k = t; k < c; k += 256) pairs[base + k] = buf[o][k];
        }
        __syncthreads();  // protect bcnt/buf reuse next chunk
    }
}

// ---------------- pass 2: count + scatter, XCD-ownership chunk stealing ----------------
// Blocks drain their hardware XCD's octant first ((my+rr)&7 order), so octant r's
// cnt/fill/colA lines are written (almost) exclusively from XCD r. All control flow
// feeding __syncthreads goes through LDS (sch) -> every barrier is block-uniform
// (R9 deadlocked on a per-thread racing-counter `continue` around a barrier).
// Exhausted octants cost one probe atomic per block; completeness never depends on
// block->XCD placement (G16).

__global__ void count_o(const uint2* __restrict__ pairs, const int* __restrict__ octCur,
                        int* __restrict__ chunkCtr, int* __restrict__ cnt) {
    __shared__ int sch;
    const int my = get_xcc();
    for (int rr = 0; rr < 8; ++rr) {
        const int r = (my + rr) & 7;
        const int n = octCur[r * CTR_STRIDE];
        const int nch = (n + WCHUNK - 1) / WCHUNK;
        const uint2* p = pairs + (size_t)r * OCTCAP_REGION;
        while (true) {
            __syncthreads();
            if (threadIdx.x == 0) sch = atomicAdd(&chunkCtr[r * CTR_STRIDE], 1);
            __syncthreads();
            const int ch = sch;
            if (ch >= nch) break;  // uniform: sch is LDS
            const int e0 = ch * WCHUNK;
            const int e1 = (e0 + WCHUNK < n) ? e0 + WCHUNK : n;
            for (int q = e0 + threadIdx.x; q < e1; q += 256)
                atomicAdd(&cnt[p[q].x], 1);
        }
    }
}

__global__ void scatter_o(const uint2* __restrict__ pairs, const int* __restrict__ octCur,
                          int* __restrict__ chunkCtr, int* __restrict__ fill,
                          int* __restrict__ colA) {
    __shared__ int sch;
    const int my = get_xcc();
    for (int rr = 0; rr < 8; ++rr) {
        const int r = (my + rr) & 7;
        const int n = octCur[r * CTR_STRIDE];
        const int nch = (n + WCHUNK - 1) / WCHUNK;
        const uint2* p = pairs + (size_t)r * OCTCAP_REGION;
        while (true) {
            __syncthreads();
            if (threadIdx.x == 0) sch = atomicAdd(&chunkCtr[r * CTR_STRIDE], 1);
            __syncthreads();
            const int ch = sch;
            if (ch >= nch) break;  // uniform: sch is LDS
            const int e0 = ch * WCHUNK;
            const int e1 = (e0 + WCHUNK < n) ? e0 + WCHUNK : n;
            for (int q = e0 + threadIdx.x; q < e1; q += 256) {
                uint2 e = p[q];
                int pos = atomicAdd(&fill[e.x], 1);
                colA[pos] = (int)e.y;
            }
        }
    }
}

// ---------------- prefix scan over cnt -> rowptr, dinv, fill cursors ----------------

__global__ void scanA(const int* __restrict__ cnt, int* __restrict__ bsum) {
    __shared__ int ls[SCAN_BLK];
    int t = threadIdx.x;
    int base = blockIdx.x * SCAN_ITEMS + t * 4;
    int s = 0;
#pragma unroll
    for (int k = 0; k < 4; ++k) { int i = base + k; if (i < NN) s += cnt[i]; }
    ls[t] = s; __syncthreads();
    for (int off = 128; off > 0; off >>= 1) {
        if (t < off) ls[t] += ls[t + off];
        __syncthreads();
    }
    if (t == 0) bsum[blockIdx.x] = ls[0];
}

__global__ void scanB(const int* __restrict__ bsum, int* __restrict__ boff) {
    __shared__ int ls[SCAN_BLK];
    int t = threadIdx.x;
    int v = (t < NSCANBLK) ? bsum[t] : 0;
    ls[t] = v; __syncthreads();
    for (int off = 1; off < SCAN_BLK; off <<= 1) {
        int x = 0;
        if (t >= off) x = ls[t - off];
        __syncthreads();
        ls[t] += x;
        __syncthreads();
    }
    if (t < NSCANBLK) boff[t] = ls[t] - v;  // exclusive
}

__global__ void scanC(int* __restrict__ cnt /* becomes fill-start */, const int* __restrict__ boff,
                      int* __restrict__ rowptr, float* __restrict__ dinv) {
    __shared__ int ls[SCAN_BLK];
    int t = threadIdx.x;
    int base = blockIdx.x * SCAN_ITEMS + t * 4;
    int c[4]; int s = 0;
#pragma unroll
    for (int k = 0; k < 4; ++k) { int i = base + k; c[k] = (i < NN) ? cnt[i] : 0; s += c[k]; }
    ls[t] = s; __syncthreads();
    for (int off = 1; off < SCAN_BLK; off <<= 1) {
        int x = 0;
        if (t >= off) x = ls[t - off];
        __syncthreads();
        ls[t] += x;
        __syncthreads();
    }
    int run = boff[blockIdx.x] + ls[t] - s;  // exclusive base for this thread
#pragma unroll
    for (int k = 0; k < 4; ++k) {
        int i = base + k;
        if (i < NN) {
            rowptr[i] = run;
            cnt[i] = run;  // fill cursor for scatter
            dinv[i] = rsqrtf((float)(c[k] + 1));  // +1 self-loop
            run += c[k];
            if (i == NN - 1) rowptr[NN] = run;
        }
    }
}

// ---------------- x pre-scale ----------------

__global__ void scale_x(const float* __restrict__ x, const float* __restrict__ dinv,
                        __half* __restrict__ xsc) {
    int idx = blockIdx.x * blockDim.x + threadIdx.x;
    if (idx < NN * 20) {
        int n = idx / 20;
        xsc[idx] = __float2half(x[idx] * dinv[n]);
    }
}

// ---------------- GEMM: BN-affine (from raw stats) + ReLU on input; optional stats out ----------------

template <int FIN, int FOUT, bool AFFINE, bool SCALED, bool STATS>
__global__ void gemm_k(const float* __restrict__ hin,
                       const float* __restrict__ sumsIn, const float* __restrict__ ssqIn,
                       const float* __restrict__ g, const float* __restrict__ be,
                       const float* __restrict__ W, const float* __restrict__ dinv,
                       const float* __restrict__ bias,
                       float* __restrict__ outF, __half* __restrict__ outH,
                       float* __restrict__ sumsOut, float* __restrict__ ssqOut) {
    constexpr int NB = 256 / FOUT;  // nodes per group
    __shared__ float Wl[FIN * FOUT];
    __shared__ float rows[NB][FIN];
    __shared__ float aa[AFFINE ? FIN : 1], bb[AFFINE ? FIN : 1];
    const int t = threadIdx.x;
    if constexpr (AFFINE) {
        if (t < FIN) {
            float mu = sumsIn[t] / (float)NN;
            float var = ssqIn[t] / (float)NN - mu * mu;
            float a = g[t] * rsqrtf(var + BNEPS);
            aa[t] = a;
            bb[t] = be[t] - mu * a;
        }
    }
    for (int i = t; i < FIN * FOUT; i += 256) Wl[i] = W[i];
    const int c = t % FOUT, s = t / FOUT;
    const int ngrp = (NN + NB - 1) / NB;
    float sAcc = 0.f, qAcc = 0.f;
    for (int grp = blockIdx.x; grp < ngrp; grp += gridDim.x) {
        __syncthreads();
        for (int i = t; i < NB * FIN; i += 256) {
            int sn = i / FIN, k = i % FIN;
            int n2 = grp * NB + sn;
            float v = 0.f;
            if (n2 < NN) {
                v = hin[(size_t)n2 * FIN + k];
                if constexpr (AFFINE) {
                    v = aa[k] * v + bb[k];
                    v = v > 0.f ? v : 0.f;
                }
            }
            rows[sn][k] = v;
        }
        __syncthreads();
        int node = grp * NB + s;
        if (node < NN) {
            float acc = 0.f;
#pragma unroll
            for (int k = 0; k < FIN; ++k) acc += rows[s][k] * Wl[k * FOUT + c];
            if constexpr (SCALED) {
                outH[(size_t)node * FOUT + c] = __float2half(acc * dinv[node]);
            } else {
                float val = acc + bias[c];
                outF[(size_t)node * FOUT + c] = val;
                if constexpr (STATS) { sAcc += val; qAcc += val * val; }
            }
        }
    }
    if constexpr (STATS) {
        __shared__ float ls[FOUT], lq[FOUT];
        __syncthreads();
        if (t < FOUT) { ls[t] = 0.f; lq[t] = 0.f; }
        __syncthreads();
        atomicAdd(&ls[c], sAcc);
        atomicAdd(&lq[c], qAcc);
        __syncthreads();
        if (t < FOUT) { atomicAdd(&sumsOut[t], ls[t]); atomicAdd(&ssqOut[t], lq[t]); }
    }
}

// ---------------- gather aggregation, half2-per-lane, optional fused BN stats ----------------

template <int H2, int OUTF, bool STATS>
__global__ void agg_half(const __half2* __restrict__ src, const int* __restrict__ rowptr,
                         const int* __restrict__ colA, const float* __restrict__ dinv,
                         const float* __restrict__ bias, float* __restrict__ out,
                         float* __restrict__ sumsOut, float* __restrict__ ssqOut) {
    constexpr int SUB = 64 / H2;
    const int lane = threadIdx.x & 63;
    const int wid = (blockIdx.x * blockDim.x + threadIdx.x) >> 6;
    const int totalWaves = (gridDim.x * blockDim.x) >> 6;
    const int f = lane % H2;
    const int sub = lane / H2;
    const int stride = totalWaves * SUB;
    float bx = 0.f, by = 0.f;
    if (bias != nullptr) {
        bx = bias[2 * f];
        by = (2 * f + 1 < OUTF) ? bias[2 * f + 1] : 0.f;
    }
    const int i0 = (sub < SUB) ? wid * SUB + sub : NN;  // idle tail lanes skip
    float sx = 0.f, qx = 0.f, sy = 0.f, qy = 0.f;
    for (int i = i0; i < NN; i += stride) {
        const int r0 = rowptr[i], r1 = rowptr[i + 1];
        float2 acc = __half22float2(src[(size_t)i * H2 + f]);
        float2 acc2 = {0.f, 0.f};
        int e = r0;
        for (; e + 3 < r1; e += 4) {
            int j0 = colA[e], j1 = colA[e + 1], j2 = colA[e + 2], j3 = colA[e + 3];
            float2 v0 = __half22float2(src[(size_t)j0 * H2 + f]);
            float2 v1 = __half22float2(src[(size_t)j1 * H2 + f]);
            float2 v2 = __half22float2(src[(size_t)j2 * H2 + f]);
            float2 v3 = __half22float2(src[(size_t)j3 * H2 + f]);
            acc.x += v0.x + v1.x;
            acc.y += v0.y + v1.y;
            acc2.x += v2.x + v3.x;
            acc2.y += v2.y + v3.y;
        }
        for (; e < r1; ++e) {
            float2 v = __half22float2(src[(size_t)colA[e] * H2 + f]);
            acc.x += v.x; acc.y += v.y;
        }
        acc.x += acc2.x; acc.y += acc2.y;
        const float d = dinv[i];
        float vx = d * acc.x + bx;
        out[(size_t)i * OUTF + 2 * f] = vx;
        if constexpr (STATS) { sx += vx; qx += vx * vx; }
        if (2 * f + 1 < OUTF) {
            float vy = d * acc.y + by;
            out[(size_t)i * OUTF + 2 * f + 1] = vy;
            if constexpr (STATS) { sy += vy; qy += vy * vy; }
        }
    }
    if constexpr (STATS) {
        __shared__ float ls[OUTF], lq[OUTF];
        const int t = threadIdx.x;
        if (t < OUTF) { ls[t] = 0.f; lq[t] = 0.f; }
        __syncthreads();
        atomicAdd(&ls[2 * f], sx);
        atomicAdd(&lq[2 * f], qx);
        if (2 * f + 1 < OUTF) {
            atomicAdd(&ls[2 * f + 1], sy);
            atomicAdd(&lq[2 * f + 1], qy);
        }
        __syncthreads();
        if (t < OUTF) { atomicAdd(&sumsOut[t], ls[t]); atomicAdd(&ssqOut[t], lq[t]); }
    }
}

// ---------------- GAT factorized precompute ----------------

__global__ void gat_mats(const float* __restrict__ Wg, const float* __restrict__ att_src,
                         const float* __restrict__ att_dst, const float* __restrict__ Wf,
                         const float* __restrict__ bg, float* __restrict__ Psrc,
                         float* __restrict__ Pdst, float* __restrict__ M,
                         float* __restrict__ bgW) {
    int t = threadIdx.x;  // 1024 threads, one block
    if (t < 128) {
        int k = t >> 3, h = t & 7;
        float s = 0.f, d = 0.f;
        for (int c = 0; c < 16; ++c) {
            float wv = Wg[k * 128 + h * 16 + c];
            s += wv * att_src[h * 16 + c];
            d += wv * att_dst[h * 16 + c];
        }
        Psrc[k * 8 + h] = s;
        Pdst[k * 8 + h] = d;
    } else if (t < 512) {
        int m = t - 128;
        if (m < 384) {
            int hk = m / 3, j = m - hk * 3;
            int H = hk >> 4, k = hk & 15;
            float s = 0.f;
            for (int c = 0; c < 16; ++c) s += Wg[k * 128 + H * 16 + c] * Wf[c * 3 + j];
            M[hk * 3 + j] = 0.125f * s;
        }
    } else if (t < 515) {
        int j = t - 512;
        float s = 0.f;
        for (int c = 0; c < 16; ++c) s += bg[c] * Wf[c * 3 + j];
        bgW[j] = s;
    }
}

// ---------------- gat_pre2: z (fp16) + asrc/adst; BN-affine from raw stats ----------------

__global__ void gat_pre2(const float* __restrict__ h3,
                         const float* __restrict__ sums3, const float* __restrict__ ssq3,
                         const float* __restrict__ g3, const float* __restrict__ be3,
                         const float* __restrict__ Psrc, const float* __restrict__ Pdst,
                         __half* __restrict__ z, float* __restrict__ asrc,
                         float* __restrict__ adst) {
    __shared__ float Ps[128], Pd[128], aa[16], bb[16];
    int t = threadIdx.x;
    if (t < 128) { Ps[t] = Psrc[t]; Pd[t] = Pdst[t]; }
    if (t < 16) {
        float mu = sums3[t] / (float)NN;
        float var = ssq3[t] / (float)NN - mu * mu;
        float a = g3[t] * rsqrtf(var + BNEPS);
        aa[t] = a;
        bb[t] = be3[t] - mu * a;
    }
    __syncthreads();
    int n = blockIdx.x * blockDim.x + t;
    if (n >= NN) return;
    float zv[16];
#pragma unroll
    for (int k = 0; k < 16; ++k) {
        float v = h3[(size_t)n * 16 + k];
        v = aa[k] * v + bb[k];
        zv[k] = v > 0.f ? v : 0.f;
    }
    __half2 zh[8];
#pragma unroll
    for (int k = 0; k < 8; ++k) zh[k] = __floats2half2_rn(zv[2 * k], zv[2 * k + 1]);
    float4* zo = (float4*)(z + (size_t)n * 16);
    zo[0] = ((float4*)zh)[0];
    zo[1] = ((float4*)zh)[1];
    float as[8], ad[8];
#pragma unroll
    for (int h = 0; h < 8; ++h) { as[h] = 0.f; ad[h] = 0.f; }
#pragma unroll
    for (int k = 0; k < 16; ++k) {
        float zk = zv[k];
#pragma unroll
        for (int h = 0; h < 8; ++h) {
            as[h] += zk * Ps[k * 8 + h];
            ad[h] += zk * Pd[k * 8 + h];
        }
    }
    float4* a4 = (float4*)(asrc + (size_t)n * 8);
    a4[0] = make_float4(as[0], as[1], as[2], as[3]);
    a4[1] = make_float4(as[4], as[5], as[6], as[7]);
    float4* d4 = (float4*)(adst + (size_t)n * 8);
    d4[0] = make_float4(ad[0], ad[1], ad[2], ad[3]);
    d4[1] = make_float4(ad[4], ad[5], ad[6], ad[7]);
}

// ---------------- gat_agg5: per-dst per-head weighted z-sums ----------------

__device__ __forceinline__ float leaky02(float x) { return x > 0.f ? x : 0.2f * x; }

__global__ void gat_agg5(const float2* __restrict__ z2, const float* __restrict__ asrc,
                         const float* __restrict__ adst, const int* __restrict__ rowptr,
                         const int* __restrict__ colA, __half* __restrict__ Sn) {
    const int lane = threadIdx.x & 63;
    const int q = lane & 3;
    const int hh = (lane >> 2) & 1;
    const int sub = lane >> 3;
    const int wid = (blockIdx.x * blockDim.x + threadIdx.x) >> 6;
    const int totalWaves = (gridDim.x * blockDim.x) >> 6;
    const float4* asrc4 = (const float4*)asrc;
    const float4* adst4 = (const float4*)adst;
    for (int i = wid; i < NN; i += totalWaves) {
        const int r0 = rowptr[i], r1 = rowptr[i + 1];
        const float4 adh = adst4[(size_t)i * 2 + hh];
        float acc[4][4];
        float wsum[4];
        {   // self loop (sub 0 only)
            float4 a = asrc4[(size_t)i * 2 + hh];
            float2 zr = z2[(size_t)i * 4 + q];
            const __half2* zp = (const __half2*)&zr;
            float2 f0 = __half22float2(zp[0]), f1 = __half22float2(zp[1]);
            float zf[4] = {f0.x, f0.y, f1.x, f1.y};
            float wq[4];
            wq[0] = (sub == 0) ? __expf(leaky02(a.x + adh.x)) : 0.f;
            wq[1] = (sub == 0) ? __expf(leaky02(a.y + adh.y)) : 0.f;
            wq[2] = (sub == 0) ? __expf(leaky02(a.z + adh.z)) : 0.f;
            wq[3] = (sub == 0) ? __expf(leaky02(a.w + adh.w)) : 0.f;
#pragma unroll
            for (int h = 0; h < 4; ++h) {
                wsum[h] = wq[h];
#pragma unroll
                for (int k = 0; k < 4; ++k) acc[h][k] = wq[h] * zf[k];
            }
        }
        for (int e = r0; e < r1; e += 8) {
            const int ee = e + sub;
            const bool val = ee < r1;
            const int j = val ? colA[ee] : i;
            float4 a = asrc4[(size_t)j * 2 + hh];
            float2 zr = z2[(size_t)j * 4 + q];
            const __half2* zp = (const __half2*)&zr;
            float2 f0 = __half22float2(zp[0]), f1 = __half22float2(zp[1]);
            float zf[4] = {f0.x, f0.y, f1.x, f1.y};
            float wq[4];
            wq[0] = val ? __expf(leaky02(a.x + adh.x)) : 0.f;
            wq[1] = val ? __expf(leaky02(a.y + adh.y)) : 0.f;
            wq[2] = val ? __expf(leaky02(a.z + adh.z)) : 0.f;
            wq[3] = val ? __expf(leaky02(a.w + adh.w)) : 0.f;
#pragma unroll
            for (int h = 0; h < 4; ++h) {
                wsum[h] += wq[h];
#pragma unroll
                for (int k = 0; k < 4; ++k) acc[h][k] += wq[h] * zf[k];
            }
        }
#pragma unroll
        for (int off = 8; off < 64; off <<= 1) {
#pragma unroll
            for (int h = 0; h < 4; ++h) {
                wsum[h] += __shfl_xor(wsum[h], off);
#pragma unroll
                for (int k = 0; k < 4; ++k) acc[h][k] += __shfl_xor(acc[h][k], off);
            }
        }
        if (lane < 8) {  // one lane per (hh,q): writes 4 heads x 4 k
#pragma unroll
            for (int h = 0; h < 4; ++h) {
                const float inv = 1.f / wsum[h];
                __half2 o[2];
                o[0] = __floats2half2_rn(acc[h][0] * inv, acc[h][1] * inv);
                o[1] = __floats2half2_rn(acc[h][2] * inv, acc[h][3] * inv);
                *(float2*)(Sn + (size_t)i * 128 + (hh * 4 + h) * 16 + q * 4) = *(float2*)o;
            }
        }
    }
}

// ---------------- graph bounds from sorted batch ----------------

__global__ void graph_bounds(const int* __restrict__ batch, int* __restrict__ gstart) {
    int n = blockIdx.x * blockDim.x + threadIdx.x;
    if (n < NN) {
        int bn = batch[n];
        int bp = (n == 0) ? -1 : batch[n - 1];
        for (int g = bp + 1; g <= bn; ++g) gstart[g] = n;
        if (n == NN - 1)
            for (int g = bn + 1; g <= GG; ++g) gstart[g] = NN;
    }
}

// ---------------- pool + classify (fused, atomic-free): one wave per graph ----------------

__global__ void pool_final(const __half2* __restrict__ Sn2, const int* __restrict__ gstart,
                           const float* __restrict__ M, const float* __restrict__ bgW,
                           const float* __restrict__ bf, float* __restrict__ out) {
    const int lane = threadIdx.x & 63;
    const int g = (blockIdx.x * blockDim.x + threadIdx.x) >> 6;
    if (g >= GG) return;
    const int n0 = gstart[g], n1 = gstart[g + 1];
    float2 s = {0.f, 0.f};
    for (int n = n0; n < n1; ++n) {
        float2 v = __half22float2(Sn2[(size_t)n * 64 + lane]);
        s.x += v.x;
        s.y += v.y;
    }
    float o[3];
#pragma unroll
    for (int j = 0; j < 3; ++j)
        o[j] = s.x * M[(2 * lane) * 3 + j] + s.y * M[(2 * lane + 1) * 3 + j];
#pragma unroll
    for (int off = 1; off < 64; off <<= 1) {
#pragma unroll
        for (int j = 0; j < 3; ++j) o[j] += __shfl_xor(o[j], off);
    }
    if (lane == 0) {
        float cnt = (float)(n1 - n0);
#pragma unroll
        for (int j = 0; j < 3; ++j) out[g * 3 + j] = o[j] + cnt * bgW[j] + bf[j];
    }
}

// ---------------- launcher ----------------

extern "C" void kernel_launch(void* const* d_in, const int* in_sizes, int n_in,
                              void* d_out, int out_size, void* d_ws, size_t ws_size,
                              hipStream_t stream) {
    const float* x = (const float*)d_in[0];
    const int* ei = (const int*)d_in[1];
    const int* batch = (const int*)d_in[2];
    const float* W1 = (const float*)d_in[3];  const float* b1 = (const float*)d_in[4];
    const float* g1 = (const float*)d_in[5];  const float* be1 = (const float*)d_in[6];
    const float* W2 = (const float*)d_in[7];  const float* b2 = (const float*)d_in[8];
    const float* g2 = (const float*)d_in[9];  const float* be2 = (const float*)d_in[10];
    const float* W3 = (const float*)d_in[11]; const float* b3 = (const float*)d_in[12];
    const float* g3 = (const float*)d_in[13]; const float* be3 = (const float*)d_in[14];
    const float* Wg = (const float*)d_in[15];
    const float* att_src = (const float*)d_in[16];
    const float* att_dst = (const float*)d_in[17];
    const float* bg = (const float*)d_in[18];
    const float* Wf = (const float*)d_in[19];
    const float* bf = (const float*)d_in[20];
    float* out = (float*)d_out;

    char* w = (char*)d_ws;
    auto alloc = [&](size_t bytes) -> char* {
        char* p = w;
        w += (bytes + 255) & ~(size_t)255;
        return p;
    };
    // --- zeroed region (one memset) ---
    int* fill = (int*)alloc((size_t)NN * 4);
    int* octCur = (int*)alloc(8 * CTR_STRIDE * 4);
    int* chunkA = (int*)alloc(8 * CTR_STRIDE * 4);
    int* chunkB = (int*)alloc(8 * CTR_STRIDE * 4);
    float* sums1 = (float*)alloc(64 * 4); float* ssq1 = (float*)alloc(64 * 4);
    float* sums2 = (float*)alloc(32 * 4); float* ssq2 = (float*)alloc(32 * 4);
    float* sums3 = (float*)alloc(16 * 4); float* ssq3 = (float*)alloc(16 * 4);
    size_t zeroBytes = (size_t)(w - (char*)d_ws);
    // --- rest ---
    float* Psrc = (float*)alloc(128 * 4);
    float* Pdst = (float*)alloc(128 * 4);
    float* Mm = (float*)alloc(384 * 4);
    float* bgW = (float*)alloc(3 * 4);
    int* gstart = (int*)alloc((size_t)(GG + 1) * 4);
    int* bsum = (int*)alloc(128 * 4);
    int* boff = (int*)alloc(128 * 4);
    int* rowptr = (int*)alloc((size_t)(NN + 1) * 4);
    int* colA = (int*)alloc((size_t)EE * 4);
    float* dinv = (float*)alloc((size_t)NN * 4);
    char* A = alloc((size_t)NN * 64 * 4);  // 25.6 MB scratch block A
    char* B = alloc((size_t)NN * 64 * 4);  // 25.6 MB scratch block B

    // lifetime-based aliases
    uint2*  pairs = (uint2*)A;  // 26.1 MB, spans A into B head; dead before layer 1 writes
    __half* xsc  = (__half*)B;                               // [NN,20] fp16   4.0 MB
    float*  aggx = (float*)(B + (size_t)NN * 32 * 2);        // [NN,20] fp32   8.0 MB
    float*  h1   = (float*)A;                                // [NN,64] fp32  25.6 MB
    __half* hs2  = (__half*)B;                               // [NN,32] fp16   6.4 MB
    float*  h2   = (float*)(B + (size_t)NN * 32 * 2);        // [NN,32] fp32  12.8 MB
    __half* hs3  = (__half*)A;                               // [NN,16] fp16   3.2 MB
    float*  h3   = (float*)(A + (size_t)NN * 16 * 2);        // [NN,16] fp32   6.4 MB
    __half* z    = (__half*)(A + (size_t)NN * 24 * 4);       // [NN,16] fp16   3.2 MB
    float*  asrc = (float*)(A + (size_t)NN * 32 * 4);        // [NN,8]  fp32   3.2 MB
    float*  adst = (float*)(A + (size_t)NN * 40 * 4);        // [NN,8]  fp32   3.2 MB
    __half* Sn   = (__half*)B;                               // [NN,128] fp16 25.6 MB

    hipMemsetAsync(d_ws, 0, zeroBytes, stream);

    // CSR build: bin by octant (sequential writes), then XCD-owned count/scatter
    bin_edges<<<2048, 256, 0, stream>>>(ei, pairs, octCur);
    count_o<<<2048, 256, 0, stream>>>(pairs, octCur, chunkA, fill);
    scanA<<<NSCANBLK, SCAN_BLK, 0, stream>>>(fill, bsum);
    scanB<<<1, SCAN_BLK, 0, stream>>>(bsum, boff);
    scanC<<<NSCANBLK, SCAN_BLK, 0, stream>>>(fill, boff, rowptr, dinv);
    scatter_o<<<2048, 256, 0, stream>>>(pairs, octCur, chunkB, fill, colA);
    gat_mats<<<1, 1024, 0, stream>>>(Wg, att_src, att_dst, Wf, bg, Psrc, Pdst, Mm, bgW);
    graph_bounds<<<(NN + 255) / 256, 256, 0, stream>>>(batch, gstart);

    // layer 1: aggregate x first (20ch tight fp16), then GEMM 20->64 (+b1, fused BN stats)
    scale_x<<<(NN * 20 + 255) / 256, 256, 0, stream>>>(x, dinv, xsc);
    agg_half<10, 20, false><<<2048, 256, 0, stream>>>((const __half2*)xsc, rowptr, colA, dinv,
                                                      nullptr, aggx, nullptr, nullptr);
    gemm_k<20, 64, false, false, true><<<2048, 256, 0, stream>>>(
        aggx, nullptr, nullptr, nullptr, nullptr, W1, dinv, b1, h1, nullptr, sums1, ssq1);

    // layer 2: 64 -> 32 (BN affine in-kernel; agg emits BN stats)
    gemm_k<64, 32, true, true, false><<<2048, 256, 0, stream>>>(
        h1, sums1, ssq1, g1, be1, W2, dinv, nullptr, nullptr, hs2, nullptr, nullptr);
    agg_half<16, 32, true><<<2048, 256, 0, stream>>>((const __half2*)hs2, rowptr, colA, dinv,
                                                     b2, h2, sums2, ssq2);

    // layer 3: 32 -> 16
    gemm_k<32, 16, true, true, false><<<2048, 256, 0, stream>>>(
        h2, sums2, ssq2, g2, be2, W3, dinv, nullptr, nullptr, hs3, nullptr, nullptr);
    agg_half<8, 16, true><<<2048, 256, 0, stream>>>((const __half2*)hs3, rowptr, colA, dinv,
                                                    b3, h3, sums3, ssq3);

    // GAT factorized: z/asrc/adst (L2-resident gathers), per-head sums, fused pool+classify
    gat_pre2<<<(NN + 255) / 256, 256, 0, stream>>>(h3, sums3, ssq3, g3, be3, Psrc, Pdst,
                                                   z, asrc, adst);
    gat_agg5<<<2048, 256, 0, stream>>>((const float2*)z, asrc, adst, rowptr, colA, Sn);
    pool_final<<<(GG * 64 + 255) / 256, 256, 0, stream>>>((const __half2*)Sn, gstart, Mm, bgW,
                                                          bf, out);
}

// Round 11
// 516.384 us; speedup vs baseline: 1.5949x; 1.5949x over previous
//
#include <hip/hip_runtime.h>
#include <hip/hip_fp16.h>

constexpr int NN = 100000;   // nodes
constexpr int EE = 3200000;  // edges
constexpr int GG = 5000;     // graphs
constexpr float BNEPS = 1e-5f;

// CSR build via 128 dst-bins + LDS-staged scatter
constexpr int BINS = 128;
constexpr int NPB = (NN + BINS - 1) / BINS;      // 782 nodes per bin
constexpr int BCHUNK = 8192;                     // edges per bin_edges chunk
constexpr int NBCH = (EE + BCHUNK - 1) / BCHUNK; // 391
constexpr int BINCAP2 = 96;                      // LDS staging per bin per chunk (mean 64, +4σ)
constexpr int BINREG = 27648;                    // pairs region stride (mean 25000, +16σ)
constexpr int LCAP = 26624;                      // LDS colA buffer entries (mean+10σ)
constexpr int CTR_STRIDE = 32;                   // pad counters to separate lines

typedef int int4v __attribute__((ext_vector_type(4)));

// ---------------- pass 1: bin edges by dst bin (128 bins), sequential pair writes ----------------
// R10 falsified XCD-ownership as the scatter-thrash cause; real mechanism is L2 capacity:
// stream(3.2M) + colA window(1.6M) + fill > 4MB per octant. Fix: bins small enough that the
// scatter's random writes happen entirely in LDS (scatter_lds below).

__global__ __launch_bounds__(1024) void bin_edges(const int* __restrict__ ei,
                                                  uint2* __restrict__ pairs,
                                                  int* __restrict__ binCur) {
    __shared__ int bcnt[BINS];
    __shared__ int bbase[BINS];
    __shared__ uint2 buf[BINS][BINCAP2];
    const int t = threadIdx.x;
    const int lane = t & 63, wv = t >> 6;  // 16 waves
    for (int ch = blockIdx.x; ch < NBCH; ch += gridDim.x) {
        for (int k = t; k < BINS; k += 1024) bcnt[k] = 0;
        __syncthreads();
        const int qbase = ch * (BCHUNK / 4);
#pragma unroll
        for (int rep = 0; rep < 2; ++rep) {
            const int q = qbase + rep * 1024 + t;
            if (q < EE / 4) {
                int4v d = __builtin_nontemporal_load((const int4v*)(ei + EE) + q);
                int4v s = __builtin_nontemporal_load((const int4v*)ei + q);
                int dd[4] = {d.x, d.y, d.z, d.w};
                int ss[4] = {s.x, s.y, s.z, s.w};
#pragma unroll
                for (int k = 0; k < 4; ++k) {
                    int o = dd[k] / NPB;
                    int p = atomicAdd(&bcnt[o], 1);
                    if (p < BINCAP2) {
                        buf[o][p] = make_uint2((unsigned)dd[k], (unsigned)ss[k]);
                    } else {  // rare overflow: direct write
                        int gp = atomicAdd(&binCur[o * CTR_STRIDE], 1);
                        pairs[(size_t)o * BINREG + gp] =
                            make_uint2((unsigned)dd[k], (unsigned)ss[k]);
                    }
                }
            }
        }
        __syncthreads();
        if (t < BINS) {
            int c = bcnt[t] < BINCAP2 ? bcnt[t] : BINCAP2;
            bbase[t] = atomicAdd(&binCur[t * CTR_STRIDE], c);
            bcnt[t] = c;
        }
        __syncthreads();
        // flush: wave wv handles bins wv, wv+16, ... (8 bins/wave, ~64 entries each)
        for (int o = wv; o < BINS; o += 16) {
            const int c = bcnt[o];
            const size_t base = (size_t)o * BINREG + bbase[o];
            for (int k = lane; k < c; k += 64) pairs[base + k] = buf[o][k];
        }
        __syncthreads();  // protect bcnt/buf reuse
    }
}

// ---------------- exclusive scan of bin totals -> global colA bases ----------------

__global__ void bin_base(const int* __restrict__ binCur, int* __restrict__ binBase) {
    __shared__ int s[BINS];
    const int t = threadIdx.x;  // 128 threads
    const int v = binCur[t * CTR_STRIDE];
    s[t] = v;
    __syncthreads();
    for (int off = 1; off < BINS; off <<= 1) {
        int add = (t >= off) ? s[t - off] : 0;
        __syncthreads();
        s[t] += add;
        __syncthreads();
    }
    binBase[t] = s[t] - v;  // exclusive
}

// ---------------- fused count + scan + scatter, one block per bin, all-LDS ----------------
// The bin's entire colA segment (~100 KB) is built in LDS (random atomics are free of
// L2 line-thrash) then flushed sequentially. Also writes rowptr (coalesced) and dinv.

__global__ __launch_bounds__(1024) void scatter_lds(const uint2* __restrict__ pairs,
                                                    const int* __restrict__ binCur,
                                                    const int* __restrict__ binBase,
                                                    int* __restrict__ rowptr,
                                                    float* __restrict__ dinv,
                                                    int* __restrict__ colA) {
    __shared__ int scnt[NPB];     // count -> cursor
    __shared__ int sscan[1024];
    __shared__ int lbuf[LCAP];
    const int b = blockIdx.x;
    const int t = threadIdx.x;
    const int lo = b * NPB;
    const int hi = (lo + NPB < NN) ? lo + NPB : NN;
    const int nb = hi - lo;
    const int tot = binCur[b * CTR_STRIDE];
    const int base = binBase[b];
    const uint2* p = pairs + (size_t)b * BINREG;
    for (int k = t; k < nb; k += 1024) scnt[k] = 0;
    __syncthreads();
    for (int q = t; q < tot; q += 1024) atomicAdd(&scnt[p[q].x - lo], 1);
    __syncthreads();
    const int myc = (t < nb) ? scnt[t] : 0;
    sscan[t] = myc;
    __syncthreads();
    for (int off = 1; off < 1024; off <<= 1) {
        int add = (t >= off) ? sscan[t - off] : 0;
        __syncthreads();
        sscan[t] += add;
        __syncthreads();
    }
    const int excl = sscan[t] - myc;
    if (t < nb) {
        rowptr[lo + t] = base + excl;
        dinv[lo + t] = rsqrtf((float)(myc + 1));  // +1 self-loop
        scnt[t] = excl;                           // becomes fill cursor
    }
    if (b == BINS - 1 && t == 0) rowptr[NN] = base + tot;
    __syncthreads();
    for (int q = t; q < tot; q += 1024) {
        uint2 e = p[q];
        int pos = atomicAdd(&scnt[e.x - lo], 1);
        if (pos < LCAP) lbuf[pos] = (int)e.y;
        else colA[base + pos] = (int)e.y;  // overflow beyond LDS cap (never expected)
    }
    __syncthreads();
    const int m = tot < LCAP ? tot : LCAP;
    for (int k = t; k < m; k += 1024) colA[base + k] = lbuf[k];
}

// ---------------- x pre-scale ----------------

__global__ void scale_x(const float* __restrict__ x, const float* __restrict__ dinv,
                        __half* __restrict__ xsc) {
    int idx = blockIdx.x * blockDim.x + threadIdx.x;
    if (idx < NN * 20) {
        int n = idx / 20;
        xsc[idx] = __float2half(x[idx] * dinv[n]);
    }
}

// ---------------- GEMM: BN-affine (from raw stats) + ReLU on input; optional stats out ----------------

template <int FIN, int FOUT, bool AFFINE, bool SCALED, bool STATS>
__global__ void gemm_k(const float* __restrict__ hin,
                       const float* __restrict__ sumsIn, const float* __restrict__ ssqIn,
                       const float* __restrict__ g, const float* __restrict__ be,
                       const float* __restrict__ W, const float* __restrict__ dinv,
                       const float* __restrict__ bias,
                       float* __restrict__ outF, __half* __restrict__ outH,
                       float* __restrict__ sumsOut, float* __restrict__ ssqOut) {
    constexpr int NB = 256 / FOUT;  // nodes per group
    __shared__ float Wl[FIN * FOUT];
    __shared__ float rows[NB][FIN];
    __shared__ float aa[AFFINE ? FIN : 1], bb[AFFINE ? FIN : 1];
    const int t = threadIdx.x;
    if constexpr (AFFINE) {
        if (t < FIN) {
            float mu = sumsIn[t] / (float)NN;
            float var = ssqIn[t] / (float)NN - mu * mu;
            float a = g[t] * rsqrtf(var + BNEPS);
            aa[t] = a;
            bb[t] = be[t] - mu * a;
        }
    }
    for (int i = t; i < FIN * FOUT; i += 256) Wl[i] = W[i];
    const int c = t % FOUT, s = t / FOUT;
    const int ngrp = (NN + NB - 1) / NB;
    float sAcc = 0.f, qAcc = 0.f;
    for (int grp = blockIdx.x; grp < ngrp; grp += gridDim.x) {
        __syncthreads();
        for (int i = t; i < NB * FIN; i += 256) {
            int sn = i / FIN, k = i % FIN;
            int n2 = grp * NB + sn;
            float v = 0.f;
            if (n2 < NN) {
                v = hin[(size_t)n2 * FIN + k];
                if constexpr (AFFINE) {
                    v = aa[k] * v + bb[k];
                    v = v > 0.f ? v : 0.f;
                }
            }
            rows[sn][k] = v;
        }
        __syncthreads();
        int node = grp * NB + s;
        if (node < NN) {
            float acc = 0.f;
#pragma unroll
            for (int k = 0; k < FIN; ++k) acc += rows[s][k] * Wl[k * FOUT + c];
            if constexpr (SCALED) {
                outH[(size_t)node * FOUT + c] = __float2half(acc * dinv[node]);
            } else {
                float val = acc + bias[c];
                outF[(size_t)node * FOUT + c] = val;
                if constexpr (STATS) { sAcc += val; qAcc += val * val; }
            }
        }
    }
    if constexpr (STATS) {
        __shared__ float ls[FOUT], lq[FOUT];
        __syncthreads();
        if (t < FOUT) { ls[t] = 0.f; lq[t] = 0.f; }
        __syncthreads();
        atomicAdd(&ls[c], sAcc);
        atomicAdd(&lq[c], qAcc);
        __syncthreads();
        if (t < FOUT) { atomicAdd(&sumsOut[t], ls[t]); atomicAdd(&ssqOut[t], lq[t]); }
    }
}

// ---------------- gather aggregation, half2-per-lane, optional fused BN stats ----------------

template <int H2, int OUTF, bool STATS>
__global__ void agg_half(const __half2* __restrict__ src, const int* __restrict__ rowptr,
                         const int* __restrict__ colA, const float* __restrict__ dinv,
                         const float* __restrict__ bias, float* __restrict__ out,
                         float* __restrict__ sumsOut, float* __restrict__ ssqOut) {
    constexpr int SUB = 64 / H2;
    const int lane = threadIdx.x & 63;
    const int wid = (blockIdx.x * blockDim.x + threadIdx.x) >> 6;
    const int totalWaves = (gridDim.x * blockDim.x) >> 6;
    const int f = lane % H2;
    const int sub = lane / H2;
    const int stride = totalWaves * SUB;
    float bx = 0.f, by = 0.f;
    if (bias != nullptr) {
        bx = bias[2 * f];
        by = (2 * f + 1 < OUTF) ? bias[2 * f + 1] : 0.f;
    }
    const int i0 = (sub < SUB) ? wid * SUB + sub : NN;  // idle tail lanes skip
    float sx = 0.f, qx = 0.f, sy = 0.f, qy = 0.f;
    for (int i = i0; i < NN; i += stride) {
        const int r0 = rowptr[i], r1 = rowptr[i + 1];
        float2 acc = __half22float2(src[(size_t)i * H2 + f]);
        float2 acc2 = {0.f, 0.f};
        int e = r0;
        for (; e + 3 < r1; e += 4) {
            int j0 = colA[e], j1 = colA[e + 1], j2 = colA[e + 2], j3 = colA[e + 3];
            float2 v0 = __half22float2(src[(size_t)j0 * H2 + f]);
            float2 v1 = __half22float2(src[(size_t)j1 * H2 + f]);
            float2 v2 = __half22float2(src[(size_t)j2 * H2 + f]);
            float2 v3 = __half22float2(src[(size_t)j3 * H2 + f]);
            acc.x += v0.x + v1.x;
            acc.y += v0.y + v1.y;
            acc2.x += v2.x + v3.x;
            acc2.y += v2.y + v3.y;
        }
        for (; e < r1; ++e) {
            float2 v = __half22float2(src[(size_t)colA[e] * H2 + f]);
            acc.x += v.x; acc.y += v.y;
        }
        acc.x += acc2.x; acc.y += acc2.y;
        const float d = dinv[i];
        float vx = d * acc.x + bx;
        out[(size_t)i * OUTF + 2 * f] = vx;
        if constexpr (STATS) { sx += vx; qx += vx * vx; }
        if (2 * f + 1 < OUTF) {
            float vy = d * acc.y + by;
            out[(size_t)i * OUTF + 2 * f + 1] = vy;
            if constexpr (STATS) { sy += vy; qy += vy * vy; }
        }
    }
    if constexpr (STATS) {
        __shared__ float ls[OUTF], lq[OUTF];
        const int t = threadIdx.x;
        if (t < OUTF) { ls[t] = 0.f; lq[t] = 0.f; }
        __syncthreads();
        atomicAdd(&ls[2 * f], sx);
        atomicAdd(&lq[2 * f], qx);
        if (2 * f + 1 < OUTF) {
            atomicAdd(&ls[2 * f + 1], sy);
            atomicAdd(&lq[2 * f + 1], qy);
        }
        __syncthreads();
        if (t < OUTF) { atomicAdd(&sumsOut[t], ls[t]); atomicAdd(&ssqOut[t], lq[t]); }
    }
}

// ---------------- GAT factorized precompute ----------------

__global__ void gat_mats(const float* __restrict__ Wg, const float* __restrict__ att_src,
                         const float* __restrict__ att_dst, const float* __restrict__ Wf,
                         const float* __restrict__ bg, float* __restrict__ Psrc,
                         float* __restrict__ Pdst, float* __restrict__ M,
                         float* __restrict__ bgW) {
    int t = threadIdx.x;  // 1024 threads, one block
    if (t < 128) {
        int k = t >> 3, h = t & 7;
        float s = 0.f, d = 0.f;
        for (int c = 0; c < 16; ++c) {
            float wv = Wg[k * 128 + h * 16 + c];
            s += wv * att_src[h * 16 + c];
            d += wv * att_dst[h * 16 + c];
        }
        Psrc[k * 8 + h] = s;
        Pdst[k * 8 + h] = d;
    } else if (t < 512) {
        int m = t - 128;
        if (m < 384) {
            int hk = m / 3, j = m - hk * 3;
            int H = hk >> 4, k = hk & 15;
            float s = 0.f;
            for (int c = 0; c < 16; ++c) s += Wg[k * 128 + H * 16 + c] * Wf[c * 3 + j];
            M[hk * 3 + j] = 0.125f * s;
        }
    } else if (t < 515) {
        int j = t - 512;
        float s = 0.f;
        for (int c = 0; c < 16; ++c) s += bg[c] * Wf[c * 3 + j];
        bgW[j] = s;
    }
}

// ---------------- gat_pre2: z (fp16) + asrc/adst; BN-affine from raw stats ----------------

__global__ void gat_pre2(const float* __restrict__ h3,
                         const float* __restrict__ sums3, const float* __restrict__ ssq3,
                         const float* __restrict__ g3, const float* __restrict__ be3,
                         const float* __restrict__ Psrc, const float* __restrict__ Pdst,
                         __half* __restrict__ z, float* __restrict__ asrc,
                         float* __restrict__ adst) {
    __shared__ float Ps[128], Pd[128], aa[16], bb[16];
    int t = threadIdx.x;
    if (t < 128) { Ps[t] = Psrc[t]; Pd[t] = Pdst[t]; }
    if (t < 16) {
        float mu = sums3[t] / (float)NN;
        float var = ssq3[t] / (float)NN - mu * mu;
        float a = g3[t] * rsqrtf(var + BNEPS);
        aa[t] = a;
        bb[t] = be3[t] - mu * a;
    }
    __syncthreads();
    int n = blockIdx.x * blockDim.x + t;
    if (n >= NN) return;
    float zv[16];
#pragma unroll
    for (int k = 0; k < 16; ++k) {
        float v = h3[(size_t)n * 16 + k];
        v = aa[k] * v + bb[k];
        zv[k] = v > 0.f ? v : 0.f;
    }
    __half2 zh[8];
#pragma unroll
    for (int k = 0; k < 8; ++k) zh[k] = __floats2half2_rn(zv[2 * k], zv[2 * k + 1]);
    float4* zo = (float4*)(z + (size_t)n * 16);
    zo[0] = ((float4*)zh)[0];
    zo[1] = ((float4*)zh)[1];
    float as[8], ad[8];
#pragma unroll
    for (int h = 0; h < 8; ++h) { as[h] = 0.f; ad[h] = 0.f; }
#pragma unroll
    for (int k = 0; k < 16; ++k) {
        float zk = zv[k];
#pragma unroll
        for (int h = 0; h < 8; ++h) {
            as[h] += zk * Ps[k * 8 + h];
            ad[h] += zk * Pd[k * 8 + h];
        }
    }
    float4* a4 = (float4*)(asrc + (size_t)n * 8);
    a4[0] = make_float4(as[0], as[1], as[2], as[3]);
    a4[1] = make_float4(as[4], as[5], as[6], as[7]);
    float4* d4 = (float4*)(adst + (size_t)n * 8);
    d4[0] = make_float4(ad[0], ad[1], ad[2], ad[3]);
    d4[1] = make_float4(ad[4], ad[5], ad[6], ad[7]);
}

// ---------------- gat_agg5: per-dst per-head weighted z-sums ----------------

__device__ __forceinline__ float leaky02(float x) { return x > 0.f ? x : 0.2f * x; }

__global__ void gat_agg5(const float2* __restrict__ z2, const float* __restrict__ asrc,
                         const float* __restrict__ adst, const int* __restrict__ rowptr,
                         const int* __restrict__ colA, __half* __restrict__ Sn) {
    const int lane = threadIdx.x & 63;
    const int q = lane & 3;
    const int hh = (lane >> 2) & 1;
    const int sub = lane >> 3;
    const int wid = (blockIdx.x * blockDim.x + threadIdx.x) >> 6;
    const int totalWaves = (gridDim.x * blockDim.x) >> 6;
    const float4* asrc4 = (const float4*)asrc;
    const float4* adst4 = (const float4*)adst;
    for (int i = wid; i < NN; i += totalWaves) {
        const int r0 = rowptr[i], r1 = rowptr[i + 1];
        const float4 adh = adst4[(size_t)i * 2 + hh];
        float acc[4][4];
        float wsum[4];
        {   // self loop (sub 0 only)
            float4 a = asrc4[(size_t)i * 2 + hh];
            float2 zr = z2[(size_t)i * 4 + q];
            const __half2* zp = (const __half2*)&zr;
            float2 f0 = __half22float2(zp[0]), f1 = __half22float2(zp[1]);
            float zf[4] = {f0.x, f0.y, f1.x, f1.y};
            float wq[4];
            wq[0] = (sub == 0) ? __expf(leaky02(a.x + adh.x)) : 0.f;
            wq[1] = (sub == 0) ? __expf(leaky02(a.y + adh.y)) : 0.f;
            wq[2] = (sub == 0) ? __expf(leaky02(a.z + adh.z)) : 0.f;
            wq[3] = (sub == 0) ? __expf(leaky02(a.w + adh.w)) : 0.f;
#pragma unroll
            for (int h = 0; h < 4; ++h) {
                wsum[h] = wq[h];
#pragma unroll
                for (int k = 0; k < 4; ++k) acc[h][k] = wq[h] * zf[k];
            }
        }
        for (int e = r0; e < r1; e += 8) {
            const int ee = e + sub;
            const bool val = ee < r1;
            const int j = val ? colA[ee] : i;
            float4 a = asrc4[(size_t)j * 2 + hh];
            float2 zr = z2[(size_t)j * 4 + q];
            const __half2* zp = (const __half2*)&zr;
            float2 f0 = __half22float2(zp[0]), f1 = __half22float2(zp[1]);
            float zf[4] = {f0.x, f0.y, f1.x, f1.y};
            float wq[4];
            wq[0] = val ? __expf(leaky02(a.x + adh.x)) : 0.f;
            wq[1] = val ? __expf(leaky02(a.y + adh.y)) : 0.f;
            wq[2] = val ? __expf(leaky02(a.z + adh.z)) : 0.f;
            wq[3] = val ? __expf(leaky02(a.w + adh.w)) : 0.f;
#pragma unroll
            for (int h = 0; h < 4; ++h) {
                wsum[h] += wq[h];
#pragma unroll
                for (int k = 0; k < 4; ++k) acc[h][k] += wq[h] * zf[k];
            }
        }
#pragma unroll
        for (int off = 8; off < 64; off <<= 1) {
#pragma unroll
            for (int h = 0; h < 4; ++h) {
                wsum[h] += __shfl_xor(wsum[h], off);
#pragma unroll
                for (int k = 0; k < 4; ++k) acc[h][k] += __shfl_xor(acc[h][k], off);
            }
        }
        if (lane < 8) {  // one lane per (hh,q): writes 4 heads x 4 k
#pragma unroll
            for (int h = 0; h < 4; ++h) {
                const float inv = 1.f / wsum[h];
                __half2 o[2];
                o[0] = __floats2half2_rn(acc[h][0] * inv, acc[h][1] * inv);
                o[1] = __floats2half2_rn(acc[h][2] * inv, acc[h][3] * inv);
                *(float2*)(Sn + (size_t)i * 128 + (hh * 4 + h) * 16 + q * 4) = *(float2*)o;
            }
        }
    }
}

// ---------------- graph bounds from sorted batch ----------------

__global__ void graph_bounds(const int* __restrict__ batch, int* __restrict__ gstart) {
    int n = blockIdx.x * blockDim.x + threadIdx.x;
    if (n < NN) {
        int bn = batch[n];
        int bp = (n == 0) ? -1 : batch[n - 1];
        for (int g = bp + 1; g <= bn; ++g) gstart[g] = n;
        if (n == NN - 1)
            for (int g = bn + 1; g <= GG; ++g) gstart[g] = NN;
    }
}

// ---------------- pool + classify (fused, atomic-free): one wave per graph ----------------

__global__ void pool_final(const __half2* __restrict__ Sn2, const int* __restrict__ gstart,
                           const float* __restrict__ M, const float* __restrict__ bgW,
                           const float* __restrict__ bf, float* __restrict__ out) {
    const int lane = threadIdx.x & 63;
    const int g = (blockIdx.x * blockDim.x + threadIdx.x) >> 6;
    if (g >= GG) return;
    const int n0 = gstart[g], n1 = gstart[g + 1];
    float2 s = {0.f, 0.f};
    for (int n = n0; n < n1; ++n) {
        float2 v = __half22float2(Sn2[(size_t)n * 64 + lane]);
        s.x += v.x;
        s.y += v.y;
    }
    float o[3];
#pragma unroll
    for (int j = 0; j < 3; ++j)
        o[j] = s.x * M[(2 * lane) * 3 + j] + s.y * M[(2 * lane + 1) * 3 + j];
#pragma unroll
    for (int off = 1; off < 64; off <<= 1) {
#pragma unroll
        for (int j = 0; j < 3; ++j) o[j] += __shfl_xor(o[j], off);
    }
    if (lane == 0) {
        float cnt = (float)(n1 - n0);
#pragma unroll
        for (int j = 0; j < 3; ++j) out[g * 3 + j] = o[j] + cnt * bgW[j] + bf[j];
    }
}

// ---------------- launcher ----------------

extern "C" void kernel_launch(void* const* d_in, const int* in_sizes, int n_in,
                              void* d_out, int out_size, void* d_ws, size_t ws_size,
                              hipStream_t stream) {
    const float* x = (const float*)d_in[0];
    const int* ei = (const int*)d_in[1];
    const int* batch = (const int*)d_in[2];
    const float* W1 = (const float*)d_in[3];  const float* b1 = (const float*)d_in[4];
    const float* g1 = (const float*)d_in[5];  const float* be1 = (const float*)d_in[6];
    const float* W2 = (const float*)d_in[7];  const float* b2 = (const float*)d_in[8];
    const float* g2 = (const float*)d_in[9];  const float* be2 = (const float*)d_in[10];
    const float* W3 = (const float*)d_in[11]; const float* b3 = (const float*)d_in[12];
    const float* g3 = (const float*)d_in[13]; const float* be3 = (const float*)d_in[14];
    const float* Wg = (const float*)d_in[15];
    const float* att_src = (const float*)d_in[16];
    const float* att_dst = (const float*)d_in[17];
    const float* bg = (const float*)d_in[18];
    const float* Wf = (const float*)d_in[19];
    const float* bf = (const float*)d_in[20];
    float* out = (float*)d_out;

    char* w = (char*)d_ws;
    auto alloc = [&](size_t bytes) -> char* {
        char* p = w;
        w += (bytes + 255) & ~(size_t)255;
        return p;
    };
    // --- zeroed region (one memset) ---
    int* binCur = (int*)alloc((size_t)BINS * CTR_STRIDE * 4);
    float* sums1 = (float*)alloc(64 * 4); float* ssq1 = (float*)alloc(64 * 4);
    float* sums2 = (float*)alloc(32 * 4); float* ssq2 = (float*)alloc(32 * 4);
    float* sums3 = (float*)alloc(16 * 4); float* ssq3 = (float*)alloc(16 * 4);
    size_t zeroBytes = (size_t)(w - (char*)d_ws);
    // --- rest ---
    int* binBase = (int*)alloc((size_t)BINS * 4);
    float* Psrc = (float*)alloc(128 * 4);
    float* Pdst = (float*)alloc(128 * 4);
    float* Mm = (float*)alloc(384 * 4);
    float* bgW = (float*)alloc(3 * 4);
    int* gstart = (int*)alloc((size_t)(GG + 1) * 4);
    int* rowptr = (int*)alloc((size_t)(NN + 1) * 4);
    int* colA = (int*)alloc((size_t)EE * 4);
    float* dinv = (float*)alloc((size_t)NN * 4);
    char* A = alloc((size_t)NN * 64 * 4);  // 25.6 MB scratch block A
    char* B = alloc((size_t)NN * 64 * 4);  // 25.6 MB scratch block B

    // lifetime-based aliases
    uint2*  pairs = (uint2*)A;  // BINS*BINREG*8 = 28.3 MB, spans A + head of B;
                                // dead before layer 1 writes anything
    __half* xsc  = (__half*)B;                               // [NN,20] fp16   4.0 MB
    float*  aggx = (float*)(B + (size_t)NN * 32 * 2);        // [NN,20] fp32   8.0 MB
    float*  h1   = (float*)A;                                // [NN,64] fp32  25.6 MB
    __half* hs2  = (__half*)B;                               // [NN,32] fp16   6.4 MB
    float*  h2   = (float*)(B + (size_t)NN * 32 * 2);        // [NN,32] fp32  12.8 MB
    __half* hs3  = (__half*)A;                               // [NN,16] fp16   3.2 MB
    float*  h3   = (float*)(A + (size_t)NN * 16 * 2);        // [NN,16] fp32   6.4 MB
    __half* z    = (__half*)(A + (size_t)NN * 24 * 4);       // [NN,16] fp16   3.2 MB
    float*  asrc = (float*)(A + (size_t)NN * 32 * 4);        // [NN,8]  fp32   3.2 MB
    float*  adst = (float*)(A + (size_t)NN * 40 * 4);        // [NN,8]  fp32   3.2 MB
    __half* Sn   = (__half*)B;                               // [NN,128] fp16 25.6 MB

    hipMemsetAsync(d_ws, 0, zeroBytes, stream);

    // CSR build: 128-bin pass (sequential writes) + all-LDS count/scan/scatter
    bin_edges<<<256, 1024, 0, stream>>>(ei, pairs, binCur);
    bin_base<<<1, BINS, 0, stream>>>(binCur, binBase);
    scatter_lds<<<BINS, 1024, 0, stream>>>(pairs, binCur, binBase, rowptr, dinv, colA);
    gat_mats<<<1, 1024, 0, stream>>>(Wg, att_src, att_dst, Wf, bg, Psrc, Pdst, Mm, bgW);
    graph_bounds<<<(NN + 255) / 256, 256, 0, stream>>>(batch, gstart);

    // layer 1: aggregate x first (20ch tight fp16), then GEMM 20->64 (+b1, fused BN stats)
    scale_x<<<(NN * 20 + 255) / 256, 256, 0, stream>>>(x, dinv, xsc);
    agg_half<10, 20, false><<<2048, 256, 0, stream>>>((const __half2*)xsc, rowptr, colA, dinv,
                                                      nullptr, aggx, nullptr, nullptr);
    gemm_k<20, 64, false, false, true><<<2048, 256, 0, stream>>>(
        aggx, nullptr, nullptr, nullptr, nullptr, W1, dinv, b1, h1, nullptr, sums1, ssq1);

    // layer 2: 64 -> 32 (BN affine in-kernel; agg emits BN stats)
    gemm_k<64, 32, true, true, false><<<2048, 256, 0, stream>>>(
        h1, sums1, ssq1, g1, be1, W2, dinv, nullptr, nullptr, hs2, nullptr, nullptr);
    agg_half<16, 32, true><<<2048, 256, 0, stream>>>((const __half2*)hs2, rowptr, colA, dinv,
                                                     b2, h2, sums2, ssq2);

    // layer 3: 32 -> 16
    gemm_k<32, 16, true, true, false><<<2048, 256, 0, stream>>>(
        h2, sums2, ssq2, g2, be2, W3, dinv, nullptr, nullptr, hs3, nullptr, nullptr);
    agg_half<8, 16, true><<<2048, 256, 0, stream>>>((const __half2*)hs3, rowptr, colA, dinv,
                                                    b3, h3, sums3, ssq3);

    // GAT factorized: z/asrc/adst (L2-resident gathers), per-head sums, fused pool+classify
    gat_pre2<<<(NN + 255) / 256, 256, 0, stream>>>(h3, sums3, ssq3, g3, be3, Psrc, Pdst,
                                                   z, asrc, adst);
    gat_agg5<<<2048, 256, 0, stream>>>((const float2*)z, asrc, adst, rowptr, colA, Sn);
    pool_final<<<(GG * 64 + 255) / 256, 256, 0, stream>>>((const __half2*)Sn, gstart, Mm, bgW,
                                                          bf, out);
}